// Round 1
// baseline (246.326 us; speedup 1.0000x reference)
//
#include <hip/hip_runtime.h>

// TSAdaptivePatcher: x[64][64][8192] f32, mask[64][8192] i32
// PATCH=STRIDE=16 -> n_patches=512, non-overlapping windows => pure transpose
// out = [ patches: 64*512*1024 f32 ][ padding_mask: 64*512 f32 ]

constexpr int Bb  = 64;
constexpr int Cc  = 64;
constexpr int Ss  = 8192;
constexpr int NP  = 512;   // 1 + (8192-16)/16
constexpr size_t PATCH_ELEMS = (size_t)Bb * NP * Cc * 16; // 33,554,432

__global__ __launch_bounds__(256) void ts_patcher_kernel(
    const float* __restrict__ x,
    const int*   __restrict__ mask,
    float*       __restrict__ out)
{
    // block: 256 threads = 64 c-lanes x 4 p ; grid: Bb * (NP/4) = 8192 blocks
    const int t     = threadIdx.x;
    const int c     = t & 63;       // lane within wave -> c (store-contiguous)
    const int pq    = t >> 6;       // 0..3 (wave id within block)
    const int blk   = blockIdx.x;
    const int b     = blk >> 7;     // / 128
    const int ptile = blk & 127;
    const int p     = ptile * 4 + pq;

    // load: 64B contiguous chunk x[b][c][p*16 .. p*16+16)
    const float4* src = (const float4*)(x + ((size_t)(b * Cc + c) * Ss + p * 16));
    float4 v0 = src[0];
    float4 v1 = src[1];
    float4 v2 = src[2];
    float4 v3 = src[3];

    // store: 64B contiguous chunk patches[b][p][c*16 .. c*16+16)
    float4* dst = (float4*)(out + ((size_t)(b * NP + p) * (Cc * 16) + c * 16));
    dst[0] = v0;
    dst[1] = v1;
    dst[2] = v2;
    dst[3] = v3;

    // fused padding mask: one lane per p (c==0 lanes; 4 per block)
    if (c == 0) {
        const int4* m = (const int4*)(mask + (size_t)b * Ss + p * 16);
        int4 a = m[0], d = m[1], e = m[2], f = m[3];
        int s = a.x + a.y + a.z + a.w
              + d.x + d.y + d.z + d.w
              + e.x + e.y + e.z + e.w
              + f.x + f.y + f.z + f.w;
        // mean >= 0.5  <=>  sum >= 8  (mask values in {0,1})
        out[PATCH_ELEMS + (size_t)b * NP + p] = (s >= 8) ? 1.0f : 0.0f;
    }
}

extern "C" void kernel_launch(void* const* d_in, const int* in_sizes, int n_in,
                              void* d_out, int out_size, void* d_ws, size_t ws_size,
                              hipStream_t stream) {
    const float* x    = (const float*)d_in[0];
    const int*   mask = (const int*)d_in[1];
    float*       out  = (float*)d_out;

    const int blocks = Bb * (NP / 4); // 8192
    ts_patcher_kernel<<<blocks, 256, 0, stream>>>(x, mask, out);
}

// Round 2
// 235.501 us; speedup vs baseline: 1.0460x; 1.0460x over previous
//
#include <hip/hip_runtime.h>

// TSAdaptivePatcher: x[64][64][8192] f32, mask[64][8192] i32
// PATCH=STRIDE=16 -> n_patches=512, non-overlapping => pure (c,p)-chunk transpose
// out = [ patches: 64*512*1024 f32 ][ padding_mask: 64*512 f32 ]
//
// Lane remap for coalescing: one WAVE per output row (b,p). Iteration k:
//   lane l stores out_row[k*256 + l*4 .. +4)            -> 1 KB contiguous/instr
//   lane l loads  x[b][k*16 + l/4][p*16 + (l%4)*4 .. +4) -> 16x 64B segments/instr
// (vs previous kernel's 16B-at-64B-stride pattern = 4x more transactions)

constexpr int Bb  = 64;
constexpr int Cc  = 64;
constexpr int Ss  = 8192;
constexpr int NP  = 512;   // 1 + (8192-16)/16
constexpr size_t PATCH_ELEMS = (size_t)Bb * NP * Cc * 16; // 33,554,432

__global__ __launch_bounds__(256) void ts_patcher_kernel(
    const float* __restrict__ x,
    const int*   __restrict__ mask,
    float*       __restrict__ out)
{
    const int t    = threadIdx.x;
    const int lane = t & 63;
    const int w    = t >> 6;            // wave id 0..3
    const int blk  = blockIdx.x;
    const int b    = blk >> 7;          // / 128
    const int p    = (blk & 127) * 4 + w;  // output row index (4 consecutive p per block)

    const float* xb = x + (size_t)b * Cc * Ss;
    float* orow = out + ((size_t)(b * NP + p) * (Cc * 16));

    const int cbase = lane >> 2;        // 0..15
    const int j     = (lane & 3) * 4;   // 0,4,8,12
    const int xoff  = p * 16 + j;

#pragma unroll
    for (int k = 0; k < 4; ++k) {
        const int c = k * 16 + cbase;
        const float4 v = *(const float4*)(xb + (size_t)c * Ss + xoff);
        *(float4*)(orow + k * 256 + lane * 4) = v;
    }

    // fused padding mask: lane 0 of each wave handles its row's 16 mask ints
    if (lane == 0) {
        const int4* m = (const int4*)(mask + (size_t)b * Ss + p * 16);
        int4 a = m[0], d = m[1], e = m[2], f = m[3];
        int s = a.x + a.y + a.z + a.w
              + d.x + d.y + d.z + d.w
              + e.x + e.y + e.z + e.w
              + f.x + f.y + f.z + f.w;
        // mean >= 0.5  <=>  sum >= 8  (mask values in {0,1})
        out[PATCH_ELEMS + (size_t)b * NP + p] = (s >= 8) ? 1.0f : 0.0f;
    }
}

extern "C" void kernel_launch(void* const* d_in, const int* in_sizes, int n_in,
                              void* d_out, int out_size, void* d_ws, size_t ws_size,
                              hipStream_t stream) {
    const float* x    = (const float*)d_in[0];
    const int*   mask = (const int*)d_in[1];
    float*       out  = (float*)d_out;

    const int blocks = Bb * (NP / 4); // 8192 blocks x 256 threads = 1 wave per row
    ts_patcher_kernel<<<blocks, 256, 0, stream>>>(x, mask, out);
}

// Round 3
// 228.161 us; speedup vs baseline: 1.0796x; 1.0322x over previous
//
#include <hip/hip_runtime.h>

// TSAdaptivePatcher: x[64][64][8192] f32, mask[64][8192] i32
// PATCH=STRIDE=16 -> n_patches=512, non-overlapping => pure (c,p)-chunk transpose
// out = [ patches: 64*512*1024 f32 ][ padding_mask: 64*512 f32 ]
//
// LDS-staged tile transpose. Tile = (b fixed) x (all 64 c) x (8 patches) = 32 KB.
//  Phase 1 (global->LDS): linear tile sweep; per wave-instr = 2 contiguous 512B
//    segments (8 line-requests/KB = optimal).
//  Phase 2 (LDS->global): the tile's 8 output rows are 32 KB fully contiguous in
//    out; per wave-instr = 1 KB contiguous store (optimal).
//  LDS stride 132 (=128+4): both phases hit each 4-bank group exactly 8x per
//    b128 instr = the inherent 1KB/128B minimum (no excess conflicts).

constexpr int Bb  = 64;
constexpr int Cc  = 64;
constexpr int Ss  = 8192;
constexpr int NP  = 512;     // 1 + (8192-16)/16
constexpr int PT  = 8;       // patches per tile
constexpr int ROWF = PT * 16;          // 128 floats of each c-row per tile
constexpr int LSTRIDE = ROWF + 4;      // 132, pad to rotate banks per c-row
constexpr size_t PATCH_ELEMS = (size_t)Bb * NP * Cc * 16; // 33,554,432

__global__ __launch_bounds__(256) void ts_patcher_kernel(
    const float* __restrict__ x,
    const int*   __restrict__ mask,
    float*       __restrict__ out)
{
    __shared__ float lds[Cc * LSTRIDE];   // 64*132*4 = 33792 B

    const int t   = threadIdx.x;
    const int blk = blockIdx.x;
    const int b   = blk >> 6;             // / (NP/PT) = /64
    const int P0  = (blk & 63) * PT;      // first patch of tile

    const float* xb = x + (size_t)b * Cc * Ss + P0 * 16;

    // ---- Phase 1: global -> LDS (linear tile sweep) ----
    // iter i covers tile floats [i*1024, i*1024+1024) = c-rows [i*8, i*8+8)
    {
        const int c0  = t >> 5;           // t/32: row within the 8-row group
        const int col = (t & 31) * 4;     // 0..124
#pragma unroll
        for (int i = 0; i < 8; ++i) {
            const int c = i * 8 + c0;
            const float4 v = *(const float4*)(xb + (size_t)c * Ss + col);
            *(float4*)(&lds[c * LSTRIDE + col]) = v;
        }
    }

    __syncthreads();

    // ---- Phase 2: LDS -> global (8 contiguous 4 KB output rows = 32 KB) ----
    // iter i writes output row (b, P0+i); thread t covers floats [4t, 4t+4)
    {
        float* otile = out + ((size_t)(b * NP + P0) * (Cc * 16));
        const int c = t >> 2;             // t/4
        const int j = (t & 3) * 4;
#pragma unroll
        for (int i = 0; i < 8; ++i) {
            const float4 v = *(const float4*)(&lds[c * LSTRIDE + i * 16 + j]);
            *(float4*)(otile + (size_t)i * 1024 + t * 4) = v;
        }
    }

    // ---- Fused padding mask: threads 0..7, one patch each ----
    if (t < PT) {
        const int p = P0 + t;
        const int4* m = (const int4*)(mask + (size_t)b * Ss + p * 16);
        int4 a = m[0], d = m[1], e = m[2], f = m[3];
        int s = a.x + a.y + a.z + a.w
              + d.x + d.y + d.z + d.w
              + e.x + e.y + e.z + e.w
              + f.x + f.y + f.z + f.w;
        // mean >= 0.5  <=>  sum >= 8  (mask values in {0,1})
        out[PATCH_ELEMS + (size_t)b * NP + p] = (s >= 8) ? 1.0f : 0.0f;
    }
}

extern "C" void kernel_launch(void* const* d_in, const int* in_sizes, int n_in,
                              void* d_out, int out_size, void* d_ws, size_t ws_size,
                              hipStream_t stream) {
    const float* x    = (const float*)d_in[0];
    const int*   mask = (const int*)d_in[1];
    float*       out  = (float*)d_out;

    const int blocks = Bb * (NP / PT);   // 64 * 64 = 4096
    ts_patcher_kernel<<<blocks, 256, 0, stream>>>(x, mask, out);
}